// Round 11
// baseline (89.406 us; speedup 1.0000x reference)
//
#include <hip/hip_runtime.h>

#define D 300
#define HDIM 512
#define ROWS 128          // X rows per block (grid 512 = 2 blocks/CU)
#define WPB 64            // words per block
#define NKS 20            // K-steps of 16
#define NCH 48            // 32 Q/K alternating + 16 V chunks, 32 cols each
#define CH_BYTES 20480    // 32 cols * 320 k * 2 B
#define CH_ELEMS 10240
#define SEGW 5            // 1KB staging segments per wave per chunk (20/4)

typedef __attribute__((ext_vector_type(16))) float f32x16;
typedef __attribute__((ext_vector_type(4))) float f32x4;
typedef __attribute__((ext_vector_type(8))) short bf16x8;

__device__ inline unsigned short f2bf(float f) {
  unsigned int u = __float_as_uint(f);
  unsigned int r = (u + 0x7fffu + ((u >> 16) & 1u)) >> 16;
  return (unsigned short)r;
}

__device__ inline void gload_lds16(const void* g, void* l) {
  __builtin_amdgcn_global_load_lds(
      (const __attribute__((address_space(1))) unsigned int*)g,
      (__attribute__((address_space(3))) unsigned int*)l, 16, 0, 0);
}

// Chunk layout (R10-proven conflict-free): chunk c = [ks20][kh2][col32][e8],
// lane reads its 32x32x16 B-frag at byte hi*512 + lo5*16 + ks*1024 ->
// wave64 reads 1024 contiguous bytes = no bank conflicts (R10: 7.9M -> 24K).
// c<32: even c = Wq cols (c>>1)*32, odd c = Wk cols (c>>1)*32;
// c>=32: Wv cols (c-32)*32.  k>=300 zero-padded.
__global__ __launch_bounds__(512) void prep_weights(
    const float* __restrict__ Wq, const float* __restrict__ Wk,
    const float* __restrict__ Wv, unsigned short* __restrict__ wt) {
  int idx = blockIdx.x * 512 + threadIdx.x;
  if (idx >= NCH * CH_ELEMS) return;
  int c = idx / CH_ELEMS, r2 = idx - c * CH_ELEMS;
  int ks = r2 >> 9, r3 = r2 & 511;
  int kh = r3 >> 8, r4 = r3 & 255;
  int col = r4 >> 3, e = r4 & 7;
  int k = ks * 16 + kh * 8 + e;
  const float* M; int gcol;
  if (c < 32) { M = (c & 1) ? Wk : Wq; gcol = (c >> 1) * 32 + col; }
  else        { M = Wv; gcol = (c - 32) * 32 + col; }
  float v = (k < D) ? M[k * HDIM + gcol] : 0.0f;
  wt[idx] = f2bf(v);
}

// 4-wave blocks, 2 independent barrier domains per CU (grid 512).
// Triple-buffered counted-vmcnt pipeline (T4), 32x32x16 MFMA.
// NOTE: no 2nd __launch_bounds__ arg (R4-R6: halves VGPR pool -> spill).
__global__ __launch_bounds__(256) void fused_attn(
    const float* __restrict__ charv, const float* __restrict__ wordv,
    const unsigned short* __restrict__ wt,
    const float* __restrict__ bk, const float* __restrict__ bq,
    const float* __restrict__ bv, float* __restrict__ out) {
  extern __shared__ char lds[];
  float* biasL = (float*)(lds + 3 * CH_BYTES);  // [1536]
  float* sS    = biasL + 1536;                  // [64 w][4]; reused as sAt
  float* sAt   = sS;                            // aliased (per-thread R->W, barrier-separated)

  const int tid  = threadIdx.x;
  const int wid  = tid >> 6;    // 0..3
  const int lane = tid & 63;
  const int lo5  = lane & 31;
  const int hi   = lane >> 5;

  auto stage = [&](int t) {
    const char* src = (const char*)wt + (long)t * CH_BYTES + wid * (SEGW * 1024) + lane * 16;
    char* dst = lds + (t % 3) * CH_BYTES + wid * (SEGW * 1024);
#pragma unroll
    for (int j = 0; j < SEGW; ++j)
      gload_lds16(src + j * 1024, dst + j * 1024);
  };

  // ---- prologue: biases -> LDS, X -> regs (32x32x16 A-frags), stage 0,1
  for (int i = tid; i < 1536; i += 256) {
    float v = (i < 512) ? bq[i] : ((i < 1024) ? bk[i - 512] : bv[i - 1024]);
    biasL[i] = v;
  }
  // A-frag: lane holds A[row=lo5][k=ks*16+hi*8+e]; wave rows wid*32..+32
  bf16x8 a[NKS];
  {
    int row = blockIdx.x * ROWS + wid * 32 + lo5;
    const float* rp = ((row & 1) ? charv : wordv) + (row >> 1) * D;
#pragma unroll
    for (int ks = 0; ks < NKS; ++ks) {
      int k0 = ks * 16 + hi * 8;
      float4 lo = {0.f, 0.f, 0.f, 0.f}, hif = {0.f, 0.f, 0.f, 0.f};
      if (k0 + 8 <= D) {
        lo  = *(const float4*)(rp + k0);
        hif = *(const float4*)(rp + k0 + 4);
      } else if (k0 < D) {
        lo  = *(const float4*)(rp + k0);
      }
      bf16x8 v;
      v[0] = (short)f2bf(lo.x);  v[1] = (short)f2bf(lo.y);
      v[2] = (short)f2bf(lo.z);  v[3] = (short)f2bf(lo.w);
      v[4] = (short)f2bf(hif.x); v[5] = (short)f2bf(hif.y);
      v[6] = (short)f2bf(hif.z); v[7] = (short)f2bf(hif.w);
      a[ks] = v;
    }
  }
  stage(0);
  stage(1);

  // score partials: p[tt*4 + i*2 + j], lane owns 8 words (2 rows each)
  float p[32];
#pragma unroll
  for (int t = 0; t < 32; ++t) p[t] = 0.f;

  f32x16 accQ;

  // ---- Phase A: 32 alternating Q/K chunks (16 pairs), 1 barrier each
  for (int g = 0; g < 16; ++g) {
    // t = 2g : Q chunk
    asm volatile("s_waitcnt vmcnt(5)" ::: "memory");    // stage(2g) landed; 2g+1 in flight
    asm volatile("s_waitcnt lgkmcnt(0)" ::: "memory");
    __builtin_amdgcn_s_barrier();
    stage(2 * g + 2);
    {
      const char* base = lds + ((2 * g) % 3) * CH_BYTES + hi * 512 + lo5 * 16;
      float bqv = biasL[g * 32 + lo5];
#pragma unroll
      for (int r = 0; r < 16; ++r) accQ[r] = bqv;
#pragma unroll
      for (int ks = 0; ks < NKS; ++ks) {
        bf16x8 qb = *(const bf16x8*)(base + ks * 1024);
        accQ = __builtin_amdgcn_mfma_f32_32x32x16_bf16(a[ks], qb, accQ, 0, 0, 0);
      }
    }
    // t = 2g+1 : K chunk
    asm volatile("s_waitcnt vmcnt(5)" ::: "memory");
    asm volatile("s_waitcnt lgkmcnt(0)" ::: "memory");
    __builtin_amdgcn_s_barrier();
    stage(2 * g + 3);
    {
      const char* base = lds + ((2 * g + 1) % 3) * CH_BYTES + hi * 512 + lo5 * 16;
      float bkv = biasL[512 + g * 32 + lo5];
      f32x16 accK;
#pragma unroll
      for (int r = 0; r < 16; ++r) accK[r] = bkv;
#pragma unroll
      for (int ks = 0; ks < NKS; ++ks) {
        bf16x8 kb = *(const bf16x8*)(base + ks * 1024);
        accK = __builtin_amdgcn_mfma_f32_32x32x16_bf16(a[ks], kb, accK, 0, 0, 0);
      }
      // lane-local: regs (2tt,2tt+1) = the 2 rows of word wid*16+(tt>>1)*4+(tt&1)+hi*2
#pragma unroll
      for (int tt = 0; tt < 8; ++tt)
#pragma unroll
        for (int i = 0; i < 2; ++i)
#pragma unroll
          for (int j = 0; j < 2; ++j)
            p[tt * 4 + i * 2 + j] += accQ[2 * tt + i] * accK[2 * tt + j];
    }
  }

  // ---- reduce over 32 col-lanes (xor masks keep hi fixed), write scores
#pragma unroll
  for (int t = 0; t < 32; ++t) {
    float v = p[t];
    v += __shfl_xor(v, 1);
    v += __shfl_xor(v, 2);
    v += __shfl_xor(v, 4);
    v += __shfl_xor(v, 8);
    v += __shfl_xor(v, 16);
    p[t] = v;
  }
  if (lo5 == 0) {
#pragma unroll
    for (int tt = 0; tt < 8; ++tt) {
      int w = wid * 16 + (tt >> 1) * 4 + (tt & 1) + hi * 2;
#pragma unroll
      for (int q = 0; q < 4; ++q) sS[w * 4 + q] = p[tt * 4 + q];
    }
  }
  asm volatile("s_waitcnt lgkmcnt(0)" ::: "memory");
  __builtin_amdgcn_s_barrier();   // plain barrier: stage(32),(33) stay in flight
  if (tid < 64) {
    const float sc = 0.044194173824159216f;  // 1/sqrt(512)
    float s[4];
#pragma unroll
    for (int t = 0; t < 4; ++t) s[t] = sS[tid * 4 + t] * sc;
#pragma unroll
    for (int i = 0; i < 2; ++i) {
      float m  = fmaxf(s[i * 2], s[i * 2 + 1]);
      float e0 = expf(s[i * 2] - m), e1 = expf(s[i * 2 + 1] - m);
      float inv = 1.0f / (e0 + e1);
      sAt[tid * 4 + i * 2]     = e0 * inv;
      sAt[tid * 4 + i * 2 + 1] = e1 * inv;
    }
  }
  asm volatile("s_waitcnt lgkmcnt(0)" ::: "memory");
  __builtin_amdgcn_s_barrier();

  // attention weights for this lane's 8 words
  f32x4 at[8];
#pragma unroll
  for (int tt = 0; tt < 8; ++tt) {
    int w = wid * 16 + (tt >> 1) * 4 + (tt & 1) + hi * 2;
    at[tt] = *(const f32x4*)(sAt + w * 4);
  }

  // ---- Phase B: 16 V chunks; vmcnt(21) = 5 stage + 16 stores newer
  for (int t = 32; t < NCH; ++t) {
    if (t == 32) asm volatile("s_waitcnt vmcnt(5)" ::: "memory");
    else         asm volatile("s_waitcnt vmcnt(21)" ::: "memory");
    asm volatile("s_waitcnt lgkmcnt(0)" ::: "memory");
    __builtin_amdgcn_s_barrier();
    if (t + 2 < NCH) stage(t + 2);
    const char* base = lds + (t % 3) * CH_BYTES + hi * 512 + lo5 * 16;
    const int g = t - 32;
    float bvv = biasL[1024 + g * 32 + lo5];
    f32x16 accV;
#pragma unroll
    for (int r = 0; r < 16; ++r) accV[r] = bvv;
#pragma unroll
    for (int ks = 0; ks < NKS; ++ks) {
      bf16x8 vb = *(const bf16x8*)(base + ks * 1024);
      accV = __builtin_amdgcn_mfma_f32_32x32x16_bf16(a[ks], vb, accV, 0, 0, 0);
    }
    int h = g * 32 + lo5;
#pragma unroll
    for (int tt = 0; tt < 8; ++tt) {
      int w = wid * 16 + (tt >> 1) * 4 + (tt & 1) + hi * 2;
      long gw = (long)(blockIdx.x * WPB + w);
      float v0 = accV[2 * tt], v1 = accV[2 * tt + 1];
      out[gw * 1024 + h]       = at[tt][0] * v0 + at[tt][1] * v1;
      out[gw * 1024 + 512 + h] = at[tt][2] * v0 + at[tt][3] * v1;
    }
  }
}

extern "C" void kernel_launch(void* const* d_in, const int* in_sizes, int n_in,
                              void* d_out, int out_size, void* d_ws, size_t ws_size,
                              hipStream_t stream) {
  const float* charv = (const float*)d_in[0];
  const float* wordv = (const float*)d_in[1];
  const float* Wk = (const float*)d_in[2];
  const float* bk = (const float*)d_in[3];
  const float* Wq = (const float*)d_in[4];
  const float* bq = (const float*)d_in[5];
  const float* Wv = (const float*)d_in[6];
  const float* bv = (const float*)d_in[7];
  float* out = (float*)d_out;
  unsigned short* wt = (unsigned short*)d_ws;  // 48*10240*2 = 983,040 B

  prep_weights<<<(NCH * CH_ELEMS + 511) / 512, 512, 0, stream>>>(Wq, Wk, Wv, wt);

  const int lds_bytes = 3 * CH_BYTES + 1536 * 4 + 512 * 4;  // 69,632 B -> 2 blocks/CU
  fused_attn<<<65536 / ROWS, 256, lds_bytes, stream>>>(charv, wordv, wt, bk, bq, bv, out);
}